// Round 7
// baseline (159.281 us; speedup 1.0000x reference)
//
#include <hip/hip_runtime.h>
#include <math.h>

// Problem constants: B=2, T=2048, C=1024, H=16, Dh=64
#define GB 2
#define GT_SEQ 2048
#define GC 1024
#define GH 16
#define GDH 64
#define GM (GB * GT_SEQ)      // 4096 rows

typedef __attribute__((ext_vector_type(8))) short bf16x8;   // 8 bf16 = 4 VGPRs
typedef __attribute__((ext_vector_type(8))) unsigned short u16x8;
typedef __attribute__((ext_vector_type(4))) float f32x4;

#define QSCALE 0.18033688f   // 0.125 * log2(e): QK^T lands in log2 domain

__device__ __forceinline__ unsigned short f2bf(float f) {   // RNE f32 -> bf16
    unsigned int u = __float_as_uint(f);
    u += 0x7FFFu + ((u >> 16) & 1u);
    return (unsigned short)(u >> 16);
}
__device__ __forceinline__ float bf2f(unsigned short u) {   // exact bf16 -> f32
    return __uint_as_float(((unsigned int)u) << 16);
}
__device__ __forceinline__ float hw_exp2(float x) {         // v_exp_f32
    return __builtin_amdgcn_exp2f(x);
}

// async global->LDS, 16B per lane; LDS dest is wave-uniform base (+lane*16 by HW)
#define GLOAD_LDS16(g, l) __builtin_amdgcn_global_load_lds( \
    (const __attribute__((address_space(1))) void*)(g),      \
    (__attribute__((address_space(3))) void*)(l), 16, 0, 0)

// swizzled fragment read: rows of 64 bf16 (128B = 8 chunks), chunk ^= (row&7)
__device__ __forceinline__ bf16x8 frag_ld(const char* base, int r, int kch) {
    return *reinterpret_cast<const bf16x8*>(base + r * 128 + ((kch ^ (r & 7)) << 4));
}

// ---------------- cast f32 -> bf16 ----------------
__global__ __launch_bounds__(256) void cast_f32_bf16(
    const float* __restrict__ in, unsigned short* __restrict__ out, int n)
{
    const int i = (blockIdx.x * 256 + threadIdx.x) * 4;
    if (i + 3 < n) {
        const float4 v = *reinterpret_cast<const float4*>(&in[i]);
        ushort4 o;
        o.x = f2bf(v.x); o.y = f2bf(v.y); o.z = f2bf(v.z); o.w = f2bf(v.w);
        *reinterpret_cast<ushort4*>(&out[i]) = o;
    }
}

// ---------------- bf16 MFMA GEMM: C = A @ B^T + bias (validated rounds 2-6) ----------------
__global__ __launch_bounds__(256) void gemm_mfma_bt(
    const unsigned short* __restrict__ A,   // [M][K] bf16
    const unsigned short* __restrict__ B,   // [N][K] bf16
    const float* __restrict__ bias,         // [N] f32
    float* __restrict__ Cf,                 // f32 out
    int M, int N, int K)
{
    __shared__ char As[128 * 128];
    __shared__ char Bs[128 * 128];

    const int tid  = threadIdx.x;
    const int lane = tid & 63;
    const int w    = tid >> 6;
    const int wm   = w >> 1;
    const int wn   = w & 1;
    const int m0 = blockIdx.y * 128;
    const int n0 = blockIdx.x * 128;

    f32x4 acc[4][4];
#pragma unroll
    for (int i = 0; i < 4; ++i)
#pragma unroll
        for (int j = 0; j < 4; ++j) acc[i][j] = (f32x4){0.f, 0.f, 0.f, 0.f};

    const int wbase = (tid & ~63);

    for (int k0 = 0; k0 < K; k0 += 64) {
        const char* Ag = (const char*)(A + (size_t)m0 * K + k0);
        const char* Bg = (const char*)(B + (size_t)n0 * K + k0);
#pragma unroll
        for (int i = 0; i < 4; ++i) {
            const int c = i * 256 + tid;
            const int row = c >> 3, cin = c & 7;
            const size_t goff = (size_t)row * (K * 2) + (size_t)((cin ^ (row & 7)) << 4);
            GLOAD_LDS16(Ag + goff, As + (i * 256 + wbase) * 16);
            GLOAD_LDS16(Bg + goff, Bs + (i * 256 + wbase) * 16);
        }
        __syncthreads();

#pragma unroll
        for (int ks = 0; ks < 2; ++ks) {
            const int kch = ks * 4 + (lane >> 4);
            bf16x8 a[4], b[4];
#pragma unroll
            for (int mi = 0; mi < 4; ++mi)
                a[mi] = frag_ld(As, wm * 64 + mi * 16 + (lane & 15), kch);
#pragma unroll
            for (int ni = 0; ni < 4; ++ni)
                b[ni] = frag_ld(Bs, wn * 64 + ni * 16 + (lane & 15), kch);
#pragma unroll
            for (int mi = 0; mi < 4; ++mi)
#pragma unroll
                for (int ni = 0; ni < 4; ++ni)
                    acc[mi][ni] = __builtin_amdgcn_mfma_f32_16x16x32_bf16(
                        a[mi], b[ni], acc[mi][ni], 0, 0, 0);
        }
        __syncthreads();
    }

    const int lc  = lane & 15;
    const int lr4 = (lane >> 4) * 4;
#pragma unroll
    for (int ni = 0; ni < 4; ++ni) {
        const int gcol = n0 + wn * 64 + ni * 16 + lc;
        const float bv = bias[gcol];
#pragma unroll
        for (int mi = 0; mi < 4; ++mi) {
            const int grow0 = m0 + wm * 64 + mi * 16 + lr4;
#pragma unroll
            for (int j = 0; j < 4; ++j)
                Cf[(size_t)(grow0 + j) * N + gcol] = acc[mi][ni][j] + bv;
        }
    }
}

// ---------------- GEMM1 fused: qkv projection -> per-head Qh (scaled), Kh, Vh ----------------
// Same main loop; epilogue scatters into [bh][t][d] layouts (no qkv round-trip).
__global__ __launch_bounds__(256) void gemm_qkv(
    const unsigned short* __restrict__ A,    // [4096][1024] bf16 (x)
    const unsigned short* __restrict__ B,    // [3072][1024] bf16 (w_attn)
    const float* __restrict__ bias,          // [3072]
    unsigned short* __restrict__ Qh,         // [32][2048][64]
    unsigned short* __restrict__ Kh,
    unsigned short* __restrict__ Vh)
{
    __shared__ char As[128 * 128];
    __shared__ char Bs[128 * 128];

    const int N = 3 * GC, K = GC;
    const int tid  = threadIdx.x;
    const int lane = tid & 63;
    const int w    = tid >> 6;
    const int wm   = w >> 1;
    const int wn   = w & 1;
    const int m0 = blockIdx.y * 128;
    const int n0 = blockIdx.x * 128;

    f32x4 acc[4][4];
#pragma unroll
    for (int i = 0; i < 4; ++i)
#pragma unroll
        for (int j = 0; j < 4; ++j) acc[i][j] = (f32x4){0.f, 0.f, 0.f, 0.f};

    const int wbase = (tid & ~63);

    for (int k0 = 0; k0 < K; k0 += 64) {
        const char* Ag = (const char*)(A + (size_t)m0 * K + k0);
        const char* Bg = (const char*)(B + (size_t)n0 * K + k0);
#pragma unroll
        for (int i = 0; i < 4; ++i) {
            const int c = i * 256 + tid;
            const int row = c >> 3, cin = c & 7;
            const size_t goff = (size_t)row * (K * 2) + (size_t)((cin ^ (row & 7)) << 4);
            GLOAD_LDS16(Ag + goff, As + (i * 256 + wbase) * 16);
            GLOAD_LDS16(Bg + goff, Bs + (i * 256 + wbase) * 16);
        }
        __syncthreads();

#pragma unroll
        for (int ks = 0; ks < 2; ++ks) {
            const int kch = ks * 4 + (lane >> 4);
            bf16x8 a[4], b[4];
#pragma unroll
            for (int mi = 0; mi < 4; ++mi)
                a[mi] = frag_ld(As, wm * 64 + mi * 16 + (lane & 15), kch);
#pragma unroll
            for (int ni = 0; ni < 4; ++ni)
                b[ni] = frag_ld(Bs, wn * 64 + ni * 16 + (lane & 15), kch);
#pragma unroll
            for (int mi = 0; mi < 4; ++mi)
#pragma unroll
                for (int ni = 0; ni < 4; ++ni)
                    acc[mi][ni] = __builtin_amdgcn_mfma_f32_16x16x32_bf16(
                        a[mi], b[ni], acc[mi][ni], 0, 0, 0);
        }
        __syncthreads();
    }

    const int lc  = lane & 15;
    const int lr4 = (lane >> 4) * 4;
#pragma unroll
    for (int ni = 0; ni < 4; ++ni) {
        const int gcol = n0 + wn * 64 + ni * 16 + lc;   // 0..3071
        const float bv  = bias[gcol];
        const int sel = gcol >> 10;                      // 0=q 1=k 2=v
        const int h   = (gcol >> 6) & 15;
        const int d   = gcol & 63;
        unsigned short* dst = (sel == 0) ? Qh : ((sel == 1) ? Kh : Vh);
        const float scl = (sel == 0) ? QSCALE : 1.f;
#pragma unroll
        for (int mi = 0; mi < 4; ++mi) {
            const int grow0 = m0 + wm * 64 + mi * 16 + lr4;
#pragma unroll
            for (int j = 0; j < 4; ++j) {
                const int grow = grow0 + j;
                const int bb = grow >> 11, t = grow & (GT_SEQ - 1);
                dst[((size_t)(bb * GH + h) * GT_SEQ + t) * GDH + d] =
                    f2bf((acc[mi][ni][j] + bv) * scl);
            }
        }
    }
}

// ---------------- V transpose: Vh[bh][t][d] -> Vt[bh][d][t] ----------------
__global__ __launch_bounds__(256) void transpose_v(
    const unsigned short* __restrict__ Vh, unsigned short* __restrict__ Vt)
{
    __shared__ unsigned short vt[64][72];
    const int tid = threadIdx.x;
    const int t0  = blockIdx.x * 64;
    const int bh  = blockIdx.y;
    const unsigned short* src = Vh + (size_t)bh * GT_SEQ * GDH;
    unsigned short* dstb = Vt + (size_t)bh * GDH * GT_SEQ;

#pragma unroll
    for (int i = 0; i < 2; ++i) {
        const int c = i * 256 + tid;
        const int tr = c >> 3, ch = c & 7;
        *reinterpret_cast<u16x8*>(&vt[tr][ch * 8]) =
            *reinterpret_cast<const u16x8*>(src + (size_t)(t0 + tr) * GDH + ch * 8);
    }
    __syncthreads();
#pragma unroll
    for (int i = 0; i < 2; ++i) {
        const int c = i * 256 + tid;
        const int d = c >> 3, ch = c & 7;
        u16x8 o;
#pragma unroll
        for (int e = 0; e < 8; ++e) o[e] = vt[ch * 8 + e][d];
        *reinterpret_cast<u16x8*>(dstb + (size_t)d * GT_SEQ + t0 + ch * 8) = o;
    }
}

// ---------------- flash attention v4: 2-wave K-split, barrier-free main loop ----------------
// Block = 128 threads (2 waves), one (bh, 32-row q-tile). Wave s handles key
// tiles kt ≡ s (mod 2); merge (m,l,O) at the end through LDS. Row sums via
// MFMA ones-column; deferred-max fast path; K prefetch + early V issue.
__global__ __launch_bounds__(128) void flash_attn_mfma4(
    const unsigned short* __restrict__ Qh,   // [32][2048][64], pre-scaled
    const unsigned short* __restrict__ Kh,   // [32][2048][64]
    const unsigned short* __restrict__ Vt,   // [32][64][2048]
    unsigned short* __restrict__ O)          // [4096][1024] bf16
{
    __shared__ char Ps[2][32 * 128];       // per-wave P (32 q x 64 k bf16, swizzled)
    __shared__ float Of[32][68];           // wave0's rescaled O
    __shared__ float ml_lds[2][2][32];     // [wave][m|l][row]

    const int tid  = threadIdx.x;
    const int lane = tid & 63;
    const int wv   = tid >> 6;               // 0 or 1
    const int l15  = lane & 15;
    const int l4   = lane >> 4;
    const int bid  = blockIdx.x;              // 0..2047
    // XCD swizzle: xcd (bid&7) serves heads 4*xcd..+3; heavy q-tiles first
    const int bh   = (bid & 7) * 4 + ((bid >> 3) & 3);
    const int qt   = 63 - (bid >> 5);
    const int b    = bh >> 4, h = bh & 15;
    const int q0w  = qt * 32;

    const unsigned short* hQ = Qh + (size_t)bh * GT_SEQ * GDH;
    const unsigned short* hK = Kh + (size_t)bh * GT_SEQ * GDH;
    const unsigned short* hV = Vt + (size_t)bh * GDH * GT_SEQ;
    char* myPs = Ps[wv];

    // ones B-fragment: col 0 of D = row sum
    bf16x8 ones_b;
    {
        const short ov = (l15 == 0) ? (short)0x3F80 : (short)0;
#pragma unroll
        for (int e = 0; e < 8; ++e) ones_b[e] = ov;
    }

    // Q fragments (pre-scaled): qf[mi][s], d = s*32 + l4*8 + e
    bf16x8 qf[2][2];
#pragma unroll
    for (int mi = 0; mi < 2; ++mi)
#pragma unroll
        for (int s = 0; s < 2; ++s)
            qf[mi][s] = *reinterpret_cast<const bf16x8*>(
                hQ + (size_t)(q0w + mi * 16 + l15) * GDH + s * 32 + l4 * 8);

    f32x4 acc_o[2][4];
    f32x4 acc_l[2];
    float m_r[2][4];
#pragma unroll
    for (int mi = 0; mi < 2; ++mi) {
        acc_l[mi] = (f32x4){0.f, 0.f, 0.f, 0.f};
#pragma unroll
        for (int j = 0; j < 4; ++j) m_r[mi][j] = -1e30f;
#pragma unroll
        for (int nd = 0; nd < 4; ++nd) acc_o[mi][nd] = (f32x4){0.f, 0.f, 0.f, 0.f};
    }

    const int nt = qt / 2 + 1;

    // prologue: K fragments for this wave's first tile (in-bounds even if unused)
    bf16x8 kfc[8];
    {
        const int k0p = wv * 64;
#pragma unroll
        for (int s = 0; s < 2; ++s)
#pragma unroll
            for (int ni = 0; ni < 4; ++ni)
                kfc[s * 4 + ni] = *reinterpret_cast<const bf16x8*>(
                    hK + (size_t)(k0p + ni * 16 + l15) * GDH + s * 32 + l4 * 8);
    }

    for (int kt = wv; kt < nt; kt += 2) {
        const int k0  = kt * 64;
        const int kn0 = (kt + 2 < nt ? kt + 2 : kt) * 64;

        // early V issue (consumed after softmax)
        bf16x8 vb[8];
#pragma unroll
        for (int s = 0; s < 2; ++s)
#pragma unroll
            for (int nd = 0; nd < 4; ++nd)
                vb[s * 4 + nd] = *reinterpret_cast<const bf16x8*>(
                    hV + (size_t)(nd * 16 + l15) * GT_SEQ + k0 + s * 32 + l4 * 8);

        // next-tile K prefetch
        bf16x8 kfn[8];
#pragma unroll
        for (int s = 0; s < 2; ++s)
#pragma unroll
            for (int ni = 0; ni < 4; ++ni)
                kfn[s * 4 + ni] = *reinterpret_cast<const bf16x8*>(
                    hK + (size_t)(kn0 + ni * 16 + l15) * GDH + s * 32 + l4 * 8);

        // ---- QK^T (log2 domain) ----
        f32x4 s_acc[2][4];
#pragma unroll
        for (int mi = 0; mi < 2; ++mi)
#pragma unroll
            for (int ni = 0; ni < 4; ++ni) s_acc[mi][ni] = (f32x4){0.f, 0.f, 0.f, 0.f};
#pragma unroll
        for (int s = 0; s < 2; ++s)
#pragma unroll
            for (int mi = 0; mi < 2; ++mi)
#pragma unroll
                for (int ni = 0; ni < 4; ++ni)
                    s_acc[mi][ni] = __builtin_amdgcn_mfma_f32_16x16x32_bf16(
                        qf[mi][s], kfc[s * 4 + ni], s_acc[mi][ni], 0, 0, 0);

        // ---- causal mask (diagonal tile only) ----
        if (k0 + 63 > q0w) {
#pragma unroll
            for (int mi = 0; mi < 2; ++mi)
#pragma unroll
                for (int ni = 0; ni < 4; ++ni)
#pragma unroll
                    for (int j = 0; j < 4; ++j)
                        if (k0 + ni * 16 + l15 > q0w + mi * 16 + l4 * 4 + j)
                            s_acc[mi][ni][j] = -1e30f;
        }

        // ---- deferred-max fast path ----
        float rp[2][4];
        int ok = 1;
#pragma unroll
        for (int mi = 0; mi < 2; ++mi)
#pragma unroll
            for (int j = 0; j < 4; ++j) {
                const float r = fmaxf(fmaxf(s_acc[mi][0][j], s_acc[mi][1][j]),
                                      fmaxf(s_acc[mi][2][j], s_acc[mi][3][j]));
                rp[mi][j] = r;
                ok &= (r <= m_r[mi][j] + 8.f) ? 1 : 0;
            }
        if (!__all(ok)) {
#pragma unroll
            for (int mi = 0; mi < 2; ++mi)
#pragma unroll
                for (int j = 0; j < 4; ++j) {
                    float r = rp[mi][j];
                    r = fmaxf(r, __shfl_xor(r, 1));
                    r = fmaxf(r, __shfl_xor(r, 2));
                    r = fmaxf(r, __shfl_xor(r, 4));
                    r = fmaxf(r, __shfl_xor(r, 8));
                    const float mnew = fmaxf(m_r[mi][j], r);
                    const float corr = hw_exp2(m_r[mi][j] - mnew);
                    m_r[mi][j] = mnew;
                    acc_l[mi][j] *= corr;
#pragma unroll
                    for (int nd = 0; nd < 4; ++nd) acc_o[mi][nd][j] *= corr;
                }
        }

        // ---- P = exp2(s - m) -> wave-private LDS ----
#pragma unroll
        for (int mi = 0; mi < 2; ++mi)
#pragma unroll
            for (int j = 0; j < 4; ++j) {
                const int prow  = mi * 16 + l4 * 4 + j;
                const int pbase = prow * 128;
                const int psw   = prow & 7;
#pragma unroll
                for (int ni = 0; ni < 4; ++ni) {
                    const float p = hw_exp2(s_acc[mi][ni][j] - m_r[mi][j]);
                    const int kcol = ni * 16 + l15;
                    *(unsigned short*)(myPs + pbase + (((kcol >> 3) ^ psw) << 4)
                                       + (kcol & 7) * 2) = f2bf(p);
                }
            }

        // ---- PV + row-sum column ----
#pragma unroll
        for (int s = 0; s < 2; ++s) {
            bf16x8 pa[2];
            pa[0] = frag_ld(myPs, l15,      s * 4 + l4);
            pa[1] = frag_ld(myPs, 16 + l15, s * 4 + l4);
#pragma unroll
            for (int mi = 0; mi < 2; ++mi) {
                acc_l[mi] = __builtin_amdgcn_mfma_f32_16x16x32_bf16(
                    pa[mi], ones_b, acc_l[mi], 0, 0, 0);
#pragma unroll
                for (int nd = 0; nd < 4; ++nd)
                    acc_o[mi][nd] = __builtin_amdgcn_mfma_f32_16x16x32_bf16(
                        pa[mi], vb[s * 4 + nd], acc_o[mi][nd], 0, 0, 0);
            }
        }

#pragma unroll
        for (int i = 0; i < 8; ++i) kfc[i] = kfn[i];
    }

    // ---- merge the two waves ----
    // 1) publish per-row m and l (valid in lanes l15==0)
    if (l15 == 0) {
#pragma unroll
        for (int mi = 0; mi < 2; ++mi)
#pragma unroll
            for (int j = 0; j < 4; ++j) {
                const int row = mi * 16 + l4 * 4 + j;
                ml_lds[wv][0][row] = m_r[mi][j];
                ml_lds[wv][1][row] = acc_l[mi][j];
            }
    }
    __syncthreads();

    if (wv == 0) {
        // 2) wave0 deposits its rescaled O
#pragma unroll
        for (int mi = 0; mi < 2; ++mi)
#pragma unroll
            for (int j = 0; j < 4; ++j) {
                const int row = mi * 16 + l4 * 4 + j;
                const float m1 = ml_lds[1][0][row];
                const float mm = fmaxf(m_r[mi][j], m1);
                const float s0 = hw_exp2(m_r[mi][j] - mm);
#pragma unroll
                for (int nd = 0; nd < 4; ++nd)
                    Of[row][nd * 16 + l15] = acc_o[mi][nd][j] * s0;
            }
    }
    __syncthreads();

    if (wv == 1) {
        // 3) wave1 combines and stores
#pragma unroll
        for (int mi = 0; mi < 2; ++mi)
#pragma unroll
            for (int j = 0; j < 4; ++j) {
                const int row = mi * 16 + l4 * 4 + j;
                const float m0v = ml_lds[0][0][row];
                const float l0v = ml_lds[0][1][row];
                const float l1v = ml_lds[1][1][row];
                const float mm  = fmaxf(m0v, m_r[mi][j]);
                const float s0  = hw_exp2(m0v - mm);
                const float s1  = hw_exp2(m_r[mi][j] - mm);
                const float inv = 1.f / (l0v * s0 + l1v * s1);
                const size_t rbase = (size_t)(b * GT_SEQ + q0w + row) * GC
                                   + h * GDH + l15;
#pragma unroll
                for (int nd = 0; nd < 4; ++nd)
                    O[rbase + nd * 16] =
                        f2bf((Of[row][nd * 16 + l15] + acc_o[mi][nd][j] * s1) * inv);
            }
    }
}

extern "C" void kernel_launch(void* const* d_in, const int* in_sizes, int n_in,
                              void* d_out, int out_size, void* d_ws, size_t ws_size,
                              hipStream_t stream) {
    (void)in_sizes; (void)n_in; (void)out_size; (void)ws_size;
    const float* x      = (const float*)d_in[0];
    const float* w_attn = (const float*)d_in[1];
    const float* b_attn = (const float*)d_in[2];
    const float* w_proj = (const float*)d_in[3];
    const float* b_proj = (const float*)d_in[4];
    float* out = (float*)d_out;

    unsigned short* xb  = (unsigned short*)d_ws;             // [4096][1024]
    unsigned short* wab = xb  + (size_t)GM * GC;             // [3072][1024]
    unsigned short* wpb = wab + (size_t)3 * GC * GC;         // [1024][1024]
    unsigned short* Qh  = wpb + (size_t)GC * GC;             // [32][2048][64]
    unsigned short* Kh  = Qh  + (size_t)GM * GC / 16 * 16;   // [32][2048][64]
    unsigned short* Vh  = Kh  + (size_t)GM * GDH * GH / GH * 1; // laid out below
    // (explicit arithmetic to avoid confusion: each of Qh/Kh/Vh/Vt is GM*GDH*GH/GH
    //  = 32*2048*64 = 4M elements)
    Kh = Qh + (size_t)4 * 1024 * 1024;
    Vh = Kh + (size_t)4 * 1024 * 1024;
    unsigned short* Vt  = Vh + (size_t)4 * 1024 * 1024;      // [32][64][2048]
    unsigned short* aob = xb;   // reuse: xb dead after GEMM1

    cast_f32_bf16<<<dim3(4096), dim3(256), 0, stream>>>(x,      xb,  GM * GC);
    cast_f32_bf16<<<dim3(3072), dim3(256), 0, stream>>>(w_attn, wab, 3 * GC * GC);
    cast_f32_bf16<<<dim3(1024), dim3(256), 0, stream>>>(w_proj, wpb, GC * GC);

    // 1) fused qkv projection -> Qh (scaled), Kh, Vh
    gemm_qkv<<<dim3(3 * GC / 128, GM / 128), dim3(256), 0, stream>>>(
        xb, wab, b_attn, Qh, Kh, Vh);

    // 1.5) V transpose -> Vt
    transpose_v<<<dim3(GT_SEQ / 64, GB * GH), dim3(256), 0, stream>>>(Vh, Vt);

    // 2) flash attention v4 (2-wave K-split) -> aob [B,T,C] bf16
    flash_attn_mfma4<<<dim3(GB * GH * (GT_SEQ / 32)), dim3(128), 0, stream>>>(
        Qh, Kh, Vt, aob);

    // 3) out = aob @ w_proj^T + b_proj (f32) -- reuse bf16 GEMM with bf16 A input
    gemm_mfma_bt<<<dim3(GC / 128, GM / 128), dim3(256), 0, stream>>>(
        aob, wpb, b_proj, out, GM, GC, GC);
}